// Round 1
// baseline (427.893 us; speedup 1.0000x reference)
//
#include <hip/hip_runtime.h>

#define D 128
#define MARGIN 1.0f
#define ALFA 0.1f

// ws layout (floats): [0] = triplet-loss sum, [256..383] = colsum, [512..16895] = gram
#define WS_TSUM   0
#define WS_COLSUM 256
#define WS_GRAM   512
#define WS_FLOATS (WS_GRAM + D * D)

// ---------------------------------------------------------------------------
// Kernel 1: Gram matrix G = X^T X  (128x128, K = N) + column sums.
// 256 blocks x 512 threads. Each block owns N/256 contiguous rows, stages
// 32-row chunks in LDS, per-thread 8x4 register outer-product tile,
// atomicAdd partials into ws.
// ---------------------------------------------------------------------------
__global__ __launch_bounds__(512) void gram_kernel(const float* __restrict__ emb,
                                                   int N,
                                                   float* __restrict__ ws) {
    __shared__ float lds[32][132];   // 32 rows x 128 cols, +4 pad (keeps 16B align)

    float* __restrict__ gram   = ws + WS_GRAM;
    float* __restrict__ colsum = ws + WS_COLSUM;

    const int tid = threadIdx.x;
    const int ty  = tid >> 5;    // 0..15  -> output rows  ty*8 .. ty*8+7
    const int tx  = tid & 31;    // 0..31  -> output cols  tx*4 .. tx*4+3

    float acc[8][4];
#pragma unroll
    for (int i = 0; i < 8; ++i)
#pragma unroll
        for (int j = 0; j < 4; ++j) acc[i][j] = 0.0f;

    const int colc = tid & 127;  // column this thread sums
    const int kg   = tid >> 7;   // 0..3: which 8-row slice of the chunk

    float csum = 0.0f;

    const int rowsPerBlock = N / gridDim.x;          // 262144/256 = 1024
    const int r0           = blockIdx.x * rowsPerBlock;

    for (int chunk = 0; chunk < rowsPerBlock; chunk += 32) {
        // ---- stage 32 rows (4096 floats) : 2 x float4 per thread ----
        const float4* src = (const float4*)(emb + (size_t)(r0 + chunk) * D);
#pragma unroll
        for (int it = 0; it < 2; ++it) {
            int idx = tid + it * 512;    // 0..1023 float4s in chunk
            int kk  = idx >> 5;          // 32 float4 per row
            int c4  = idx & 31;
            float4 v = src[idx];
            *(float4*)&lds[kk][c4 * 4] = v;
        }
        __syncthreads();

        // ---- outer-product accumulate ----
#pragma unroll
        for (int kk = 0; kk < 32; ++kk) {
            float a[8], b[4];
#pragma unroll
            for (int i = 0; i < 8; ++i) a[i] = lds[kk][ty * 8 + i];
#pragma unroll
            for (int j = 0; j < 4; ++j) b[j] = lds[kk][tx * 4 + j];
#pragma unroll
            for (int i = 0; i < 8; ++i)
#pragma unroll
                for (int j = 0; j < 4; ++j)
                    acc[i][j] = fmaf(a[i], b[j], acc[i][j]);
        }

        // ---- column partial sums (each thread: 8 of the 32 rows, 1 col) ----
#pragma unroll
        for (int k2 = 0; k2 < 8; ++k2) csum += lds[kg * 8 + k2][colc];

        __syncthreads();
    }

    atomicAdd(&colsum[colc], csum);
#pragma unroll
    for (int i = 0; i < 8; ++i)
#pragma unroll
        for (int j = 0; j < 4; ++j)
            atomicAdd(&gram[(ty * 8 + i) * D + tx * 4 + j], acc[i][j]);
}

// ---------------------------------------------------------------------------
// Kernel 2: triplet loss. One wave (64 lanes) per triplet; lane l handles
// elements 2l, 2l+1 via float2. Wave shfl-reduce, block LDS reduce,
// one atomicAdd per block.
// ---------------------------------------------------------------------------
__global__ __launch_bounds__(256) void triplet_kernel(const float* __restrict__ emb,
                                                      const int* __restrict__ trip,
                                                      int T,
                                                      float* __restrict__ ws) {
    const int lane   = threadIdx.x & 63;
    const int wave   = (blockIdx.x * blockDim.x + threadIdx.x) >> 6;
    const int nwaves = (gridDim.x * blockDim.x) >> 6;

    float wsum = 0.0f;

    for (int t = wave; t < T; t += nwaves) {
        const int i0 = trip[t * 3 + 0];
        const int i1 = trip[t * 3 + 1];
        const int i2 = trip[t * 3 + 2];

        const float2* p = (const float2*)(emb + (size_t)i0 * D);
        const float2* q = (const float2*)(emb + (size_t)i1 * D);
        const float2* r = (const float2*)(emb + (size_t)i2 * D);

        float2 pv = p[lane];
        float2 qv = q[lane];
        float2 rv = r[lane];

        float d1x = pv.x - qv.x, d1y = pv.y - qv.y;
        float d2x = pv.x - rv.x, d2y = pv.y - rv.y;
        float s = d1x * d1x + d1y * d1y - d2x * d2x - d2y * d2y;

#pragma unroll
        for (int off = 32; off > 0; off >>= 1) s += __shfl_xor(s, off, 64);

        if (lane == 0) wsum += fmaxf(s + MARGIN, 0.0f);
    }

    __shared__ float red[4];
    if (lane == 0) red[threadIdx.x >> 6] = wsum;
    __syncthreads();
    if (threadIdx.x == 0) {
        float b = red[0] + red[1] + red[2] + red[3];
        atomicAdd(&ws[WS_TSUM], b);
    }
}

// ---------------------------------------------------------------------------
// Kernel 3: finalize. cov = (G - N mu mu^T)/(N-1); corr^2 lower-tri mean;
// out = tsum/T + ALFA * corr_mean.
// ---------------------------------------------------------------------------
__global__ __launch_bounds__(256) void finalize_kernel(const float* __restrict__ ws,
                                                       float* __restrict__ out,
                                                       int N, int T) {
    const float* gram   = ws + WS_GRAM;
    const float* colsum = ws + WS_COLSUM;

    __shared__ float V[D];
    __shared__ float red[256];

    const int tid = threadIdx.x;
    const float invN = 1.0f / (float)N;
    const float invNm1 = 1.0f / (float)(N - 1);

    if (tid < D) {
        float m = colsum[tid] * invN;
        V[tid] = (gram[tid * D + tid] - (float)N * m * m) * invNm1;
    }
    __syncthreads();

    float local = 0.0f;
    for (int idx = tid; idx < D * D; idx += 256) {
        int i = idx >> 7, j = idx & 127;
        if (j < i) {
            float mi = colsum[i] * invN;
            float mj = colsum[j] * invN;
            float cov = (gram[idx] - (float)N * mi * mj) * invNm1;
            local += cov * cov / (V[i] * V[j]);
        }
    }
    red[tid] = local;
    __syncthreads();
    for (int s = 128; s > 0; s >>= 1) {
        if (tid < s) red[tid] += red[tid + s];
        __syncthreads();
    }
    if (tid == 0) {
        float corr_mean = red[0] / ((float)D * (float)(D - 1) * 0.5f);
        out[0] = ws[WS_TSUM] / (float)T + ALFA * corr_mean;
    }
}

extern "C" void kernel_launch(void* const* d_in, const int* in_sizes, int n_in,
                              void* d_out, int out_size, void* d_ws, size_t ws_size,
                              hipStream_t stream) {
    const float* emb  = (const float*)d_in[0];
    const int*   trip = (const int*)d_in[1];
    float*       out  = (float*)d_out;
    float*       ws   = (float*)d_ws;

    const int N = in_sizes[0] / D;   // 262144
    const int T = in_sizes[1] / 3;   // 262144

    hipMemsetAsync(d_ws, 0, WS_FLOATS * sizeof(float), stream);

    gram_kernel<<<256, 512, 0, stream>>>(emb, N, ws);
    triplet_kernel<<<2048, 256, 0, stream>>>(emb, trip, T, ws);
    finalize_kernel<<<1, 256, 0, stream>>>(ws, out, N, T);
}

// Round 3
// 291.715 us; speedup vs baseline: 1.4668x; 1.4668x over previous
//
#include <hip/hip_runtime.h>

#define D 128
#define MARGIN 1.0f
#define ALFA 0.1f
#define KC 64

// ws layout (floats):
// [0] tsum | [256..16640) gram | [16640..16768) colsum | [16896..) per-block partials
#define WS_TSUM   0
#define WS_GRAM   256
#define WS_COLSUM (WS_GRAM + D * D)
#define WS_ZERO   (WS_COLSUM + D)      // floats to zero each call
#define WS_PART   16896
#define PART_STRIDE (D * D + D)        // 16512 floats per block partial

typedef __attribute__((ext_vector_type(8)))  short bf16x8;
typedef __attribute__((ext_vector_type(16))) float f32x16;

__device__ __forceinline__ unsigned short f2bf(float f) {
    unsigned u = __float_as_uint(f);
    u += 0x7FFFu + ((u >> 16) & 1u);   // RNE
    return (unsigned short)(u >> 16);
}

// ---------------------------------------------------------------------------
// Gram via bf16 MFMA. Grid P blocks x 512 threads (8 waves). Block owns
// N/P contiguous rows; stages KC=64 rows transposed+bf16 into LDS (double
// buffered, XOR slot swizzle); wave w computes tiles (r=w&3, c=(w>>2)*2,+1)
// of the 4x4 tile grid with v_mfma_f32_32x32x16_bf16.
// A-frag(tile t): lane l reads XT[t*32+(l&31)][kb+(l>>5)*8 .. +8] — identical
// read serves as both A (row tiles) and B (col tiles) since G = X^T X.
// Gram is symmetric, so any residual row/col transpose in C/D mapping is
// harmless (G^T = G).
// ---------------------------------------------------------------------------
template<bool ATOMIC>
__global__ __launch_bounds__(512, 4) void gram_mfma(const float* __restrict__ emb,
                                                    int rowsPerBlock,
                                                    float* __restrict__ ws) {
    __shared__ __align__(16) char lds[2][128 * 128];   // 2 x (128 d-rows x 128 B)
    __shared__ float csred[D];

    const int tid = threadIdx.x;
    const int l   = tid & 63;
    const int w   = tid >> 6;
    const int r0  = blockIdx.x * rowsPerBlock;

    const int rT = w & 3;              // row tile 0..3
    const int c0 = (w >> 2) * 2;       // col tiles c0, c0+1

    f32x16 acc0 = {};
    f32x16 acc1 = {};
    float cs[4] = {0.f, 0.f, 0.f, 0.f};
    const int d0 = (tid & 31) * 4;     // dim group this thread stages

    auto stage = [&](int cc, int b) {
#pragma unroll
        for (int j = 0; j < 2; ++j) {
            const int k = j * 32 + (tid >> 5) * 2;   // even row in chunk
            const float* base = emb + (size_t)(r0 + cc * KC + k) * D + d0;
            float4 a  = *(const float4*)base;
            float4 bv = *(const float4*)(base + D);
#pragma unroll
            for (int i = 0; i < 4; ++i) {
                float av = ((const float*)&a)[i];
                float bb = ((const float*)&bv)[i];
                cs[i] += av + bb;
                unsigned slotp = (unsigned)(k >> 3) ^ (unsigned)((tid & 31) & 7); // (d>>2)&7, d=d0+i
                unsigned off = (unsigned)(d0 + i) * 128u + slotp * 16u + (unsigned)((k & 7) << 1);
                *(unsigned*)(&lds[b][off]) = (unsigned)f2bf(av) | ((unsigned)f2bf(bb) << 16);
            }
        }
    };

    auto frag = [&](int t, int kb, int b) -> bf16x8 {
        const int d = t * 32 + (l & 31);
        const int k = kb + (l >> 5) * 8;
        unsigned slotp = (unsigned)(k >> 3) ^ ((unsigned)(d >> 2) & 7u);
        return *(const bf16x8*)(&lds[b][(unsigned)d * 128u + slotp * 16u]);
    };

    const int nChunks = rowsPerBlock / KC;
    stage(0, 0);
    for (int cc = 0; cc < nChunks; ++cc) {
        const int b = cc & 1;
        __syncthreads();                       // buf b staged; buf b^1 free
        if (cc + 1 < nChunks) stage(cc + 1, b ^ 1);
#pragma unroll
        for (int kb = 0; kb < KC; kb += 16) {
            bf16x8 fr = frag(rT,     kb, b);
            bf16x8 f0 = frag(c0,     kb, b);
            bf16x8 f1 = frag(c0 + 1, kb, b);
            acc0 = __builtin_amdgcn_mfma_f32_32x32x16_bf16(fr, f0, acc0, 0, 0, 0);
            acc1 = __builtin_amdgcn_mfma_f32_32x32x16_bf16(fr, f1, acc1, 0, 0, 0);
        }
    }
    __syncthreads();

    // column sums -> LDS -> out
    if (tid < D) csred[tid] = 0.f;
    __syncthreads();
#pragma unroll
    for (int i = 0; i < 4; ++i) atomicAdd(&csred[d0 + i], cs[i]);
    __syncthreads();

    float* gram   = ATOMIC ? ws + WS_GRAM
                           : ws + WS_PART + (size_t)blockIdx.x * PART_STRIDE;
    float* colsum = ATOMIC ? ws + WS_COLSUM : gram + D * D;

    if (tid < D) {
        if (ATOMIC) atomicAdd(&colsum[tid], csred[tid]);
        else        colsum[tid] = csred[tid];
    }

    // C/D layout (verified m74/m101): col = l&31, row = (reg&3)+8*(reg>>2)+4*(l>>5)
    const int row_hi = (l >> 5) * 4;
    const int col    = l & 31;
#pragma unroll
    for (int reg = 0; reg < 16; ++reg) {
        const int row32 = (reg & 3) + 8 * (reg >> 2) + row_hi;
        const int gr    = (rT * 32 + row32) * D;
        if (ATOMIC) {
            atomicAdd(&gram[gr + c0 * 32 + col],        acc0[reg]);
            atomicAdd(&gram[gr + (c0 + 1) * 32 + col],  acc1[reg]);
        } else {
            gram[gr + c0 * 32 + col]       = acc0[reg];
            gram[gr + (c0 + 1) * 32 + col] = acc1[reg];
        }
    }
}

// ---------------------------------------------------------------------------
// Sum P block-partials into gram+colsum (atomicAdd onto zeroed region).
// grid = 65 * SLICES blocks x 256 threads.
// ---------------------------------------------------------------------------
__global__ __launch_bounds__(256) void reduce_partials(float* __restrict__ ws, int P, int slices) {
    const int nIdxBlocks = (PART_STRIDE + 255) / 256;      // 65
    const int idx   = (blockIdx.x % nIdxBlocks) * 256 + threadIdx.x;
    const int slice = blockIdx.x / nIdxBlocks;
    if (idx >= PART_STRIDE) return;
    const int per = P / slices;
    const float* part = ws + WS_PART;
    float s = 0.f;
    const int p0 = slice * per;
#pragma unroll 8
    for (int p = 0; p < per; ++p)
        s += part[(size_t)(p0 + p) * PART_STRIDE + idx];
    if (idx < D * D) atomicAdd(&ws[WS_GRAM + idx], s);
    else             atomicAdd(&ws[WS_COLSUM + (idx - D * D)], s);
}

// ---------------------------------------------------------------------------
// Triplet loss: half-wave (32 lanes, float4) per triplet, 2 triplets in
// flight per half-wave iteration.
// ---------------------------------------------------------------------------
__device__ __forceinline__ float d2diff(float4 p, float4 q, float4 r) {
    float ax = p.x - q.x, ay = p.y - q.y, az = p.z - q.z, aw = p.w - q.w;
    float bx = p.x - r.x, by = p.y - r.y, bz = p.z - r.z, bw = p.w - r.w;
    return (ax * ax + ay * ay + az * az + aw * aw)
         - (bx * bx + by * by + bz * bz + bw * bw);
}

__global__ __launch_bounds__(256, 8) void triplet_kernel(const float* __restrict__ emb,
                                                         const int* __restrict__ trip,
                                                         int T,
                                                         float* __restrict__ ws) {
    const int tid = threadIdx.x;
    const int li  = tid & 31;
    const int hw  = (blockIdx.x * blockDim.x + tid) >> 5;
    const int NH  = (gridDim.x * blockDim.x) >> 5;

    float wsum = 0.f;

    for (int t = hw; t < T; t += 2 * NH) {
        const int t2 = t + NH;
        const int i0 = trip[3 * t], i1 = trip[3 * t + 1], i2 = trip[3 * t + 2];
        float4 pv = ((const float4*)(emb + (size_t)i0 * D))[li];
        float4 qv = ((const float4*)(emb + (size_t)i1 * D))[li];
        float4 rv = ((const float4*)(emb + (size_t)i2 * D))[li];

        const bool has2 = (t2 < T);
        float4 pv2, qv2, rv2;
        if (has2) {
            const int j0 = trip[3 * t2], j1 = trip[3 * t2 + 1], j2 = trip[3 * t2 + 2];
            pv2 = ((const float4*)(emb + (size_t)j0 * D))[li];
            qv2 = ((const float4*)(emb + (size_t)j1 * D))[li];
            rv2 = ((const float4*)(emb + (size_t)j2 * D))[li];
        }

        float s = d2diff(pv, qv, rv);
#pragma unroll
        for (int off = 16; off; off >>= 1) s += __shfl_xor(s, off, 64);
        if (li == 0) wsum += fmaxf(s + MARGIN, 0.f);

        if (has2) {
            float s2 = d2diff(pv2, qv2, rv2);
#pragma unroll
            for (int off = 16; off; off >>= 1) s2 += __shfl_xor(s2, off, 64);
            if (li == 0) wsum += fmaxf(s2 + MARGIN, 0.f);
        }
    }

    __shared__ float red[8];
    if (li == 0) red[tid >> 5] = wsum;
    __syncthreads();
    if (tid == 0) {
        float b = 0.f;
#pragma unroll
        for (int i = 0; i < 8; ++i) b += red[i];
        atomicAdd(&ws[WS_TSUM], b);
    }
}

// ---------------------------------------------------------------------------
// Finalize: cov/corr^2 tril mean + combine.
// ---------------------------------------------------------------------------
__global__ __launch_bounds__(256) void finalize_kernel(const float* __restrict__ ws,
                                                       float* __restrict__ out,
                                                       int N, int T) {
    const float* gram   = ws + WS_GRAM;
    const float* colsum = ws + WS_COLSUM;

    __shared__ float V[D];
    __shared__ float red[256];

    const int tid = threadIdx.x;
    const float invN   = 1.0f / (float)N;
    const float invNm1 = 1.0f / (float)(N - 1);

    if (tid < D) {
        float m = colsum[tid] * invN;
        V[tid] = (gram[tid * D + tid] - (float)N * m * m) * invNm1;
    }
    __syncthreads();

    float local = 0.f;
    for (int idx = tid; idx < D * D; idx += 256) {
        int i = idx >> 7, j = idx & 127;
        if (j < i) {
            float mi  = colsum[i] * invN;
            float mj  = colsum[j] * invN;
            float cov = (gram[idx] - (float)N * mi * mj) * invNm1;
            local += cov * cov / (V[i] * V[j]);
        }
    }
    red[tid] = local;
    __syncthreads();
    for (int s = 128; s > 0; s >>= 1) {
        if (tid < s) red[tid] += red[tid + s];
        __syncthreads();
    }
    if (tid == 0) {
        float corr_mean = red[0] / ((float)D * (float)(D - 1) * 0.5f);
        out[0] = ws[WS_TSUM] / (float)T + ALFA * corr_mean;
    }
}

extern "C" void kernel_launch(void* const* d_in, const int* in_sizes, int n_in,
                              void* d_out, int out_size, void* d_ws, size_t ws_size,
                              hipStream_t stream) {
    const float* emb  = (const float*)d_in[0];
    const int*   trip = (const int*)d_in[1];
    float*       out  = (float*)d_out;
    float*       ws   = (float*)d_ws;

    const int N = in_sizes[0] / D;   // 262144
    const int T = in_sizes[1] / 3;   // 262144

    hipMemsetAsync(d_ws, 0, WS_ZERO * sizeof(float), stream);

    // pick partial-buffer block count by available scratch
    const size_t need512 = ((size_t)WS_PART + (size_t)512 * PART_STRIDE) * sizeof(float);
    const size_t need256 = ((size_t)WS_PART + (size_t)256 * PART_STRIDE) * sizeof(float);

    if (ws_size >= need512) {
        gram_mfma<false><<<512, 512, 0, stream>>>(emb, N / 512, ws);
        reduce_partials<<<65 * 8, 256, 0, stream>>>(ws, 512, 8);
    } else if (ws_size >= need256) {
        gram_mfma<false><<<256, 512, 0, stream>>>(emb, N / 256, ws);
        reduce_partials<<<65 * 8, 256, 0, stream>>>(ws, 256, 8);
    } else {
        gram_mfma<true><<<256, 512, 0, stream>>>(emb, N / 256, ws);
    }

    triplet_kernel<<<2048, 256, 0, stream>>>(emb, trip, T, ws);
    finalize_kernel<<<1, 256, 0, stream>>>(ws, out, N, T);
}

// Round 4
// 275.299 us; speedup vs baseline: 1.5543x; 1.0596x over previous
//
#include <hip/hip_runtime.h>

#define D 128
#define MARGIN 1.0f
#define ALFA 0.1f
#define KC 64
#define GB 512        // gram blocks
#define TBLK 1024     // triplet blocks

// ws layout (floats):
// [0] tsum | [256..16640) gram | [16640..16768) colsum | [16896..) per-block partials
#define WS_TSUM   0
#define WS_GRAM   256
#define WS_COLSUM (WS_GRAM + D * D)
#define WS_ZERO   (WS_COLSUM + D)
#define WS_PART   16896
#define PART_STRIDE (D * D + D)        // 16512 floats per gram-block partial

typedef __attribute__((ext_vector_type(8)))  short bf16x8;
typedef __attribute__((ext_vector_type(16))) float f32x16;

__device__ __forceinline__ unsigned short f2bf(float f) {
    unsigned u = __float_as_uint(f);
    u += 0x7FFFu + ((u >> 16) & 1u);   // RNE
    return (unsigned short)(u >> 16);
}

__device__ __forceinline__ float d2diff(float4 p, float4 q, float4 r) {
    float ax = p.x - q.x, ay = p.y - q.y, az = p.z - q.z, aw = p.w - q.w;
    float bx = p.x - r.x, by = p.y - r.y, bz = p.z - r.z, bw = p.w - r.w;
    return (ax * ax + ay * ay + az * az + aw * aw)
         - (bx * bx + by * by + bz * bz + bw * bw);
}

// ---------------------------------------------------------------------------
// Fused kernel, block-specialized:
//   blocks [0, GB)        : Gram via bf16 MFMA (32x32x16), per-block partials
//   blocks [GB, GB+TBLK)  : triplet loss, 4 triplets in flight per half-wave
// The two populations co-schedule on the CUs: gram is MFMA/LDS-bound,
// triplet is VMEM/L3-latency-bound -> overlap ~ max instead of sum (m114).
// Gram is symmetric (G = X^T X), so C/D row/col transposes are harmless.
// ---------------------------------------------------------------------------
template<bool ATOMIC>
__global__ __launch_bounds__(512, 4) void fused_kernel(const float* __restrict__ emb,
                                                       const int* __restrict__ trip,
                                                       int rowsPerBlock, int T,
                                                       float* __restrict__ ws) {
    __shared__ __align__(16) char lds[2][128 * 128];   // 32 KiB (gram only)
    __shared__ float csred[D];                          // gram colsums / triplet red

    const int tid = threadIdx.x;

    if (blockIdx.x < GB) {
        // ================= GRAM PATH =================
        const int l   = tid & 63;
        const int w   = tid >> 6;
        const int r0  = blockIdx.x * rowsPerBlock;

        const int rT = w & 3;              // row tile 0..3
        const int c0 = (w >> 2) * 2;       // col tiles c0, c0+1

        f32x16 acc0 = {};
        f32x16 acc1 = {};
        float cs[4] = {0.f, 0.f, 0.f, 0.f};
        const int d0 = (tid & 31) * 4;     // dim group this thread stages

        auto stage = [&](int cc, int b) {
#pragma unroll
            for (int j = 0; j < 2; ++j) {
                const int k = j * 32 + (tid >> 5) * 2;   // even row in chunk
                const float* base = emb + (size_t)(r0 + cc * KC + k) * D + d0;
                float4 a  = *(const float4*)base;
                float4 bv = *(const float4*)(base + D);
#pragma unroll
                for (int i = 0; i < 4; ++i) {
                    float av = ((const float*)&a)[i];
                    float bb = ((const float*)&bv)[i];
                    cs[i] += av + bb;
                    unsigned slotp = (unsigned)(k >> 3) ^ (unsigned)((tid & 31) & 7); // == (d>>2)&7
                    unsigned off = (unsigned)(d0 + i) * 128u + slotp * 16u + (unsigned)((k & 7) << 1);
                    *(unsigned*)(&lds[b][off]) = (unsigned)f2bf(av) | ((unsigned)f2bf(bb) << 16);
                }
            }
        };

        auto frag = [&](int t, int kb, int b) -> bf16x8 {
            const int d = t * 32 + (l & 31);
            const int k = kb + (l >> 5) * 8;
            unsigned slotp = (unsigned)(k >> 3) ^ ((unsigned)(d >> 2) & 7u);
            return *(const bf16x8*)(&lds[b][(unsigned)d * 128u + slotp * 16u]);
        };

        const int nChunks = rowsPerBlock / KC;
        stage(0, 0);
        for (int cc = 0; cc < nChunks; ++cc) {
            const int b = cc & 1;
            __syncthreads();                       // buf b staged; buf b^1 free
            if (cc + 1 < nChunks) stage(cc + 1, b ^ 1);
#pragma unroll
            for (int kb = 0; kb < KC; kb += 16) {
                bf16x8 fr = frag(rT,     kb, b);
                bf16x8 f0 = frag(c0,     kb, b);
                bf16x8 f1 = frag(c0 + 1, kb, b);
                acc0 = __builtin_amdgcn_mfma_f32_32x32x16_bf16(fr, f0, acc0, 0, 0, 0);
                acc1 = __builtin_amdgcn_mfma_f32_32x32x16_bf16(fr, f1, acc1, 0, 0, 0);
            }
        }
        __syncthreads();

        if (tid < D) csred[tid] = 0.f;
        __syncthreads();
#pragma unroll
        for (int i = 0; i < 4; ++i) atomicAdd(&csred[d0 + i], cs[i]);
        __syncthreads();

        float* gram   = ATOMIC ? ws + WS_GRAM
                               : ws + WS_PART + (size_t)blockIdx.x * PART_STRIDE;
        float* colsum = ATOMIC ? ws + WS_COLSUM : gram + D * D;

        if (tid < D) {
            if (ATOMIC) atomicAdd(&colsum[tid], csred[tid]);
            else        colsum[tid] = csred[tid];
        }

        // C/D layout (verified m74/m101): col = l&31, row = (reg&3)+8*(reg>>2)+4*(l>>5)
        const int row_hi = (l >> 5) * 4;
        const int col    = l & 31;
#pragma unroll
        for (int reg = 0; reg < 16; ++reg) {
            const int row32 = (reg & 3) + 8 * (reg >> 2) + row_hi;
            const int gr    = (rT * 32 + row32) * D;
            if (ATOMIC) {
                atomicAdd(&gram[gr + c0 * 32 + col],       acc0[reg]);
                atomicAdd(&gram[gr + (c0 + 1) * 32 + col], acc1[reg]);
            } else {
                gram[gr + c0 * 32 + col]       = acc0[reg];
                gram[gr + (c0 + 1) * 32 + col] = acc1[reg];
            }
        }
    } else {
        // ================= TRIPLET PATH =================
        const int li  = tid & 31;
        const int hwl = tid >> 5;                          // 0..15
        const int hw  = (blockIdx.x - GB) * 16 + hwl;
        const int NH  = TBLK * 16;

        float wsum = 0.f;

        for (int t0 = hw; t0 < T; t0 += 4 * NH) {
            float4 P[4], Q[4], R[4];
#pragma unroll
            for (int k = 0; k < 4; ++k) {
                const int t = t0 + k * NH;
                if (t < T) {
                    const int i0 = trip[3 * t], i1 = trip[3 * t + 1], i2 = trip[3 * t + 2];
                    P[k] = ((const float4*)(emb + (size_t)i0 * D))[li];
                    Q[k] = ((const float4*)(emb + (size_t)i1 * D))[li];
                    R[k] = ((const float4*)(emb + (size_t)i2 * D))[li];
                }
            }
#pragma unroll
            for (int k = 0; k < 4; ++k) {
                const int t = t0 + k * NH;
                if (t < T) {
                    float s = d2diff(P[k], Q[k], R[k]);
#pragma unroll
                    for (int off = 16; off; off >>= 1) s += __shfl_xor(s, off, 64);
                    if (li == 0) wsum += fmaxf(s + MARGIN, 0.f);
                }
            }
        }

        if (li == 0) csred[hwl] = wsum;
        __syncthreads();
        if (tid == 0) {
            float b = 0.f;
#pragma unroll
            for (int i = 0; i < 16; ++i) b += csred[i];
            atomicAdd(&ws[WS_TSUM], b);
        }
    }
}

// ---------------------------------------------------------------------------
// Sum GB block-partials into gram+colsum (atomicAdd onto zeroed region).
// grid = 65 * slices blocks x 256 threads.
// ---------------------------------------------------------------------------
__global__ __launch_bounds__(256) void reduce_partials(float* __restrict__ ws, int P, int slices) {
    const int nIdxBlocks = (PART_STRIDE + 255) / 256;      // 65
    const int idx   = (blockIdx.x % nIdxBlocks) * 256 + threadIdx.x;
    const int slice = blockIdx.x / nIdxBlocks;
    if (idx >= PART_STRIDE) return;
    const int per = P / slices;
    const float* part = ws + WS_PART;
    float s = 0.f;
    const int p0 = slice * per;
#pragma unroll 8
    for (int p = 0; p < per; ++p)
        s += part[(size_t)(p0 + p) * PART_STRIDE + idx];
    if (idx < D * D) atomicAdd(&ws[WS_GRAM + idx], s);
    else             atomicAdd(&ws[WS_COLSUM + (idx - D * D)], s);
}

// ---------------------------------------------------------------------------
// Finalize: cov/corr^2 tril mean + combine.
// ---------------------------------------------------------------------------
__global__ __launch_bounds__(256) void finalize_kernel(const float* __restrict__ ws,
                                                       float* __restrict__ out,
                                                       int N, int T) {
    const float* gram   = ws + WS_GRAM;
    const float* colsum = ws + WS_COLSUM;

    __shared__ float V[D];
    __shared__ float red[256];

    const int tid = threadIdx.x;
    const float invN   = 1.0f / (float)N;
    const float invNm1 = 1.0f / (float)(N - 1);

    if (tid < D) {
        float m = colsum[tid] * invN;
        V[tid] = (gram[tid * D + tid] - (float)N * m * m) * invNm1;
    }
    __syncthreads();

    float local = 0.f;
    for (int idx = tid; idx < D * D; idx += 256) {
        int i = idx >> 7, j = idx & 127;
        if (j < i) {
            float mi  = colsum[i] * invN;
            float mj  = colsum[j] * invN;
            float cov = (gram[idx] - (float)N * mi * mj) * invNm1;
            local += cov * cov / (V[i] * V[j]);
        }
    }
    red[tid] = local;
    __syncthreads();
    for (int s = 128; s > 0; s >>= 1) {
        if (tid < s) red[tid] += red[tid + s];
        __syncthreads();
    }
    if (tid == 0) {
        float corr_mean = red[0] / ((float)D * (float)(D - 1) * 0.5f);
        out[0] = ws[WS_TSUM] / (float)T + ALFA * corr_mean;
    }
}

extern "C" void kernel_launch(void* const* d_in, const int* in_sizes, int n_in,
                              void* d_out, int out_size, void* d_ws, size_t ws_size,
                              hipStream_t stream) {
    const float* emb  = (const float*)d_in[0];
    const int*   trip = (const int*)d_in[1];
    float*       out  = (float*)d_out;
    float*       ws   = (float*)d_ws;

    const int N = in_sizes[0] / D;   // 262144
    const int T = in_sizes[1] / 3;   // 262144

    hipMemsetAsync(d_ws, 0, WS_ZERO * sizeof(float), stream);

    const size_t needP = ((size_t)WS_PART + (size_t)GB * PART_STRIDE) * sizeof(float);

    if (ws_size >= needP) {
        fused_kernel<false><<<GB + TBLK, 512, 0, stream>>>(emb, trip, N / GB, T, ws);
        reduce_partials<<<65 * 16, 256, 0, stream>>>(ws, GB, 16);
    } else {
        fused_kernel<true><<<GB + TBLK, 512, 0, stream>>>(emb, trip, N / GB, T, ws);
    }

    finalize_kernel<<<1, 256, 0, stream>>>(ws, out, N, T);
}